// Round 3
// baseline (350.161 us; speedup 1.0000x reference)
//
#include <hip/hip_runtime.h>

// db1 inverse wavelet transform (grouped transposed conv, k=2, stride=2).
// x: (B=16, C=128, H=128, W=128) fp32 -> out: (B=16, G=64, 256, 256) fp32.
// out[b,g,2h+i,2w+j] = x[b,2g,h,w]*f0[i][j] + x[b,2g+1,h,w]*f1[i][j]
//
// Memory-bound streaming: 128 MiB read + 256 MiB write -> ~61 us at 6.3 TB/s.
// R3: 4 input rows per thread -> 8 loads issued before first use (deep MLP),
// 8 dense 1KiB/wave float4 stores; waves 131K -> 33K (amortize per-wave cost).

typedef float v2f __attribute__((ext_vector_type(2)));
typedef float v4f __attribute__((ext_vector_type(4)));

__global__ __launch_bounds__(256) void iwt_kernel(
    const float* __restrict__ x,
    const float* __restrict__ filt,
    float* __restrict__ out)
{
    constexpr int H = 128, W = 128;
    constexpr int HW = H * W;                 // 16384
    constexpr int OPLANE = (2 * H) * (2 * W); // 65536
    constexpr int OW = 2 * W;                 // 256
    constexpr int RPT = 4;                    // input rows per thread

    int tid = blockIdx.x * blockDim.x + threadIdx.x; // 0 .. 2097151
    int tw = tid & 63;            // w-pair index, W2=64
    int h4 = (tid >> 6) & 31;     // row-quad index, H/RPT=32
    int bg = tid >> 11;           // b*G + g, 0..1023

    // channel plane index of x0 = b*C + 2g = 2*bg
    int x0off = (2 * bg) * HW + (RPT * h4) * W + 2 * tw;

    // Issue all 8 loads up front (independent -> 8 outstanding vmem ops)
    v2f x0[RPT], x1[RPT];
#pragma unroll
    for (int r = 0; r < RPT; ++r) {
        x0[r] = __builtin_nontemporal_load((const v2f*)(x + x0off + r * W));
        x1[r] = __builtin_nontemporal_load((const v2f*)(x + x0off + r * W + HW));
    }

    // filters: f0[i][j] = filt[i*2+j], f1[i][j] = filt[4+i*2+j]
    float f000 = filt[0], f001 = filt[1], f010 = filt[2], f011 = filt[3];
    float f100 = filt[4], f101 = filt[5], f110 = filt[6], f111 = filt[7];

    int ooff = bg * OPLANE + (2 * RPT * h4) * OW + 4 * tw;
#pragma unroll
    for (int r = 0; r < RPT; ++r) {
        v4f r0, r1;
        r0.x = x0[r].x * f000 + x1[r].x * f100;
        r0.y = x0[r].x * f001 + x1[r].x * f101;
        r0.z = x0[r].y * f000 + x1[r].y * f100;
        r0.w = x0[r].y * f001 + x1[r].y * f101;

        r1.x = x0[r].x * f010 + x1[r].x * f110;
        r1.y = x0[r].x * f011 + x1[r].x * f111;
        r1.z = x0[r].y * f010 + x1[r].y * f110;
        r1.w = x0[r].y * f011 + x1[r].y * f111;

        __builtin_nontemporal_store(r0, (v4f*)(out + ooff + (2 * r) * OW));
        __builtin_nontemporal_store(r1, (v4f*)(out + ooff + (2 * r + 1) * OW));
    }
}

extern "C" void kernel_launch(void* const* d_in, const int* in_sizes, int n_in,
                              void* d_out, int out_size, void* d_ws, size_t ws_size,
                              hipStream_t stream) {
    const float* x    = (const float*)d_in[0];
    const float* filt = (const float*)d_in[1];
    float* out        = (float*)d_out;

    // total threads = 16*64*(128/4)*64 = 2097152
    constexpr int total = 16 * 64 * 32 * 64;
    constexpr int block = 256;
    iwt_kernel<<<total / block, block, 0, stream>>>(x, filt, out);
}